// Round 4
// baseline (125.116 us; speedup 1.0000x reference)
//
#include <hip/hip_runtime.h>

#define NNODES 8192
#define KZ 20
#define QB 8      // queries per block (R4: was 4)
#define NTH 512   // threads per block (R4: was 256)
#define SCAP 192  // survivor cap per query; E[n]~45, bounds-guarded

// freqs[j] = 50^(-j/10)
static constexpr float FREQS[10] = {
  1.0f, 0.67624323f, 0.45730491f, 0.30924935f, 0.20912778f,
  0.14142136f, 0.09563524f, 0.06467268f, 0.04373443f, 0.02957512f};

// output offsets (floats)
#define O_XNE  0
#define O_POS  2621440
#define O_NBP  2646016
#define O_NBD  3137536
#define O_EDGE 6414336
#define O_FE   6578176

typedef __attribute__((ext_vector_type(8))) short bfrag;   // 8 bf16 (4 VGPRs)
typedef __attribute__((ext_vector_type(4))) float f32x4;   // MFMA C/D

static __device__ __forceinline__ unsigned short f2bf(float f) {
  unsigned int u = __float_as_uint(f);
  u += 0x7fffu + ((u >> 16) & 1u);
  return (unsigned short)(u >> 16);
}
// wave64 max-reduce via DPP (verified pattern since R6), broadcast to all lanes.
static __device__ __forceinline__ float wave_max_f32(float v) {
  float t;
  t = __builtin_bit_cast(float, __builtin_amdgcn_update_dpp(__builtin_bit_cast(int, v), __builtin_bit_cast(int, v), 0x111, 0xF, 0xF, false)); v = fmaxf(v, t); // row_shr:1
  t = __builtin_bit_cast(float, __builtin_amdgcn_update_dpp(__builtin_bit_cast(int, v), __builtin_bit_cast(int, v), 0x112, 0xF, 0xF, false)); v = fmaxf(v, t); // row_shr:2
  t = __builtin_bit_cast(float, __builtin_amdgcn_update_dpp(__builtin_bit_cast(int, v), __builtin_bit_cast(int, v), 0x114, 0xF, 0xF, false)); v = fmaxf(v, t); // row_shr:4
  t = __builtin_bit_cast(float, __builtin_amdgcn_update_dpp(__builtin_bit_cast(int, v), __builtin_bit_cast(int, v), 0x118, 0xF, 0xF, false)); v = fmaxf(v, t); // row_shr:8
  t = __builtin_bit_cast(float, __builtin_amdgcn_update_dpp(__builtin_bit_cast(int, v), __builtin_bit_cast(int, v), 0x142, 0xF, 0xF, false)); v = fmaxf(v, t); // row_bcast:15
  t = __builtin_bit_cast(float, __builtin_amdgcn_update_dpp(__builtin_bit_cast(int, v), __builtin_bit_cast(int, v), 0x143, 0xF, 0xF, false)); v = fmaxf(v, t); // row_bcast:31
  return __builtin_bit_cast(float, __builtin_amdgcn_readlane(__builtin_bit_cast(int, v), 63));
}

// ---------------- prep + Wt bf16 cast (UNCHANGED R3) ----------------
// grid: 512 blocks x 256 = 131072 threads = 64*2048 wtb entries; prep rides on t<8192.
__global__ __launch_bounds__(256) void k_pre(const float* __restrict__ affines,
                                             const int* __restrict__ prot_mask,
                                             const float* __restrict__ lit,
                                             const float* __restrict__ w,
                                             float* __restrict__ out,
                                             float4* __restrict__ pos4,
                                             float4* __restrict__ ncac4,
                                             unsigned short* __restrict__ wtb) {
  int t = blockIdx.x * 256 + threadIdx.x;  // < 131072
  {  // bf16 cast of ne_weight -> wtb[64][2048] (K-contiguous, zero pad)
    int o = t >> 11, k = t & 2047;
    wtb[t] = (k < 2000) ? f2bf(w[(size_t)o * 2000 + k]) : (unsigned short)0;
  }
  if (t < NNODES) {  // prep: positions, n2, ncac
    int n = t;
    const float4* af = (const float4*)affines + (size_t)n * 3;
    float4 a0 = af[0], a1 = af[1], a2 = af[2];  // rows of rot, .w = trans
    float tx = a0.w, ty = a1.w, tz = a2.w;
    float n2;
    {
#pragma clang fp contract(off)
      // np: sum(pos*pos,-1) = ((x*x + y*y) + z*z), each op rounded, NO fma
      float xx = tx * tx;
      float yy = ty * ty;
      float zz = tz * tz;
      n2 = (xx + yy) + zz;
    }
    pos4[n] = make_float4(tx, ty, tz, n2);
    out[O_POS + n * 3 + 0] = tx;
    out[O_POS + n * 3 + 1] = ty;
    out[O_POS + n * 3 + 2] = tz;
    int aat = (prot_mask[n] != 0) ? 0 : 20;
    const float* lp = lit + aat * 9;
#pragma unroll
    for (int a = 0; a < 3; a++) {
      float l0 = lp[a * 3 + 0], l1 = lp[a * 3 + 1], l2 = lp[a * 3 + 2];
      // ncac[a][i] = sum_j rot[i][j]*lit[a][j] + trans[i]
      float x = a0.x * l0 + a0.y * l1 + a0.z * l2 + tx;
      float y = a1.x * l0 + a1.y * l1 + a1.z * l2 + ty;
      float z = a2.x * l0 + a2.y * l1 + a2.z * l2 + tz;
      ncac4[n * 3 + a] = make_float4(x, y, z, 0.f);
    }
  }
}

// ---------------- fused KNN + gather: Q=8 queries/block, 512 threads ----------------
// d2 arithmetic bit-identical to all passing rounds:
//   dot = fmaf(z_i,z_j, fmaf(y_i,y_j, x_i*x_j)); d2 = fmaf(-2, dot, n2_i+n2_j)
// R4: QB=8, NTH=512, 1024 blocks -> pos4 L2 sweep traffic halves (each sweep
// serves 8 queries). Pass 1: thread covers 16 cands (stride 512), 8 queries
// in named registers. Partition minima (64 groups = 8 threads x 16 cands =
// 128 cands, SAME granularity as before -> same pivot value distribution)
// computed in-register via __shfl_xor(1/2/4); no minb LDS. Pivot = 21st-
// smallest of 64 group minima => >=21 elements <= pivot => all true top-20
// survive; exact u64 (key<<13|idx) rank-select -> identical top-20 output.
// All 8 waves active in pivot/rank-select/gather (wave w <-> query w).
__global__ __launch_bounds__(512) void k_knng(const float4* __restrict__ pos4,
                                              const float* __restrict__ affines,
                                              const float4* __restrict__ ncac4,
                                              const float4* __restrict__ x4,
                                              float* __restrict__ out,
                                              float* __restrict__ dstg) {
  __shared__ float mca[QB][64];                  // group minima (2 KB)
  __shared__ float pivots[QB];
  __shared__ unsigned int cnt[QB];
  __shared__ unsigned long long surv[QB][SCAP];  // 12 KB
  __shared__ int nidx[QB][KZ];
  __shared__ float distbuf[QB][100];             // 3.2 KB
  __shared__ float dnbuf[QB][KZ];
  __shared__ unsigned short jobs[QB * NTH];      // (q<<9)|owner_tid (8 KB, max-sized)
  __shared__ unsigned int njobs;
  int tid = threadIdx.x;
  int lane = tid & 63, w = tid >> 6;             // w in 0..7
  int qbase = blockIdx.x * QB;
  // x-copy prefetch: issue the HBM load now, store after rank-select.
  int xq = tid >> 6, xc = tid & 63;              // 512 thr = 8 rows x 64 float4
  float4 xval = x4[(size_t)(qbase + xq) * 64 + xc];
  // query positions: wave-uniform -> scalar regs
  float4 q0 = pos4[qbase + 0], q1 = pos4[qbase + 1];
  float4 q2 = pos4[qbase + 2], q3 = pos4[qbase + 3];
  float4 q4 = pos4[qbase + 4], q5 = pos4[qbase + 5];
  float4 q6 = pos4[qbase + 6], q7 = pos4[qbase + 7];
  const float4* pp = pos4 + tid;
  float l0 = __builtin_inff(), l1 = l0, l2 = l0, l3 = l0;
  float l4 = l0, l5 = l0, l6 = l0, l7 = l0;
  {  // ---- pass 1: minima only (16 cands/thread, stride 512) ----
#pragma clang fp contract(off)
#pragma unroll 4
    for (int s = 0; s < 16; s++) {
      float4 pc = pp[s << 9];
      float d0 = fmaf(-2.0f, fmaf(q0.z, pc.z, fmaf(q0.y, pc.y, q0.x * pc.x)), q0.w + pc.w);
      float d1 = fmaf(-2.0f, fmaf(q1.z, pc.z, fmaf(q1.y, pc.y, q1.x * pc.x)), q1.w + pc.w);
      float d2 = fmaf(-2.0f, fmaf(q2.z, pc.z, fmaf(q2.y, pc.y, q2.x * pc.x)), q2.w + pc.w);
      float d3 = fmaf(-2.0f, fmaf(q3.z, pc.z, fmaf(q3.y, pc.y, q3.x * pc.x)), q3.w + pc.w);
      float d4 = fmaf(-2.0f, fmaf(q4.z, pc.z, fmaf(q4.y, pc.y, q4.x * pc.x)), q4.w + pc.w);
      float d5 = fmaf(-2.0f, fmaf(q5.z, pc.z, fmaf(q5.y, pc.y, q5.x * pc.x)), q5.w + pc.w);
      float d6 = fmaf(-2.0f, fmaf(q6.z, pc.z, fmaf(q6.y, pc.y, q6.x * pc.x)), q6.w + pc.w);
      float d7 = fmaf(-2.0f, fmaf(q7.z, pc.z, fmaf(q7.y, pc.y, q7.x * pc.x)), q7.w + pc.w);
      l0 = fminf(l0, d0); l1 = fminf(l1, d1);
      l2 = fminf(l2, d2); l3 = fminf(l3, d3);
      l4 = fminf(l4, d4); l5 = fminf(l5, d5);
      l6 = fminf(l6, d6); l7 = fminf(l7, d7);
    }
  }
  float lv[QB] = {l0, l1, l2, l3, l4, l5, l6, l7};
  {  // ---- group-of-8 minima via shfl_xor (in-register, no minb LDS) ----
#pragma unroll
    for (int q = 0; q < QB; q++) {
      float v = lv[q];
      v = fminf(v, __shfl_xor(v, 1));
      v = fminf(v, __shfl_xor(v, 2));
      v = fminf(v, __shfl_xor(v, 4));
      if ((tid & 7) == 0) mca[q][tid >> 3] = v;
    }
  }
  __syncthreads();
  {  // ---- pivot: wave w handles query w (all 8 waves active) ----
    float m = mca[w][lane];
    int c = 0;
#pragma unroll 8
    for (int j = 0; j < 64; j++) c += (mca[w][j] < m) ? 1 : 0;
    float elig = (c < KZ + 1) ? m : -__builtin_inff();
    float piv = wave_max_f32(elig);
    if (lane == 0) { pivots[w] = piv; cnt[w] = 0u; }
    if (tid == 0) njobs = 0u;
  }
  __syncthreads();
  {  // ---- job build: (q,owner) qualifies iff its pass-1 min <= pivot_q ----
#pragma unroll
    for (int q = 0; q < QB; q++) {
      if (lv[q] <= pivots[q]) {
        unsigned int ix = atomicAdd(&njobs, 1u);
        jobs[ix] = (unsigned short)((q << 9) | tid);
      }
    }
  }
  __syncthreads();
  {  // ---- pass 2 (compacted): each job rescans its owner's 16 cands, 1 query ----
#pragma clang fp contract(off)
    unsigned int nj = njobs;
    for (unsigned int j = tid; j < nj; j += NTH) {
      int job = jobs[j];
      int q = job >> 9, owner = job & 511;
      int qidx = qbase + q;
      float4 qv = pos4[qidx];      // 8 distinct addrs across block, L1-hit
      float pv = pivots[q];
      const float4* src = pos4 + owner;
#pragma unroll 8
      for (int s = 0; s < 16; s++) {
        float4 pc = src[s << 9];
        float dot = fmaf(qv.z, pc.z, fmaf(qv.y, pc.y, qv.x * pc.x));
        float d2 = fmaf(-2.0f, dot, qv.w + pc.w);
        int cc = (s << 9) + owner;
        if (d2 <= pv && cc != qidx) {
          unsigned int b = __float_as_uint(d2);
          unsigned int k = (b & 0x80000000u) ? ~b : (b | 0x80000000u);
          unsigned int ix = atomicAdd(&cnt[q], 1u);
          if (ix < SCAP)  // guard (never hit for this data)
            surv[q][ix] = ((unsigned long long)k << 13) | (unsigned int)cc;
        }
      }
    }
  }
  __syncthreads();
  {  // ---- exact rank-select: wave w handles query w ----
    unsigned int n = cnt[w]; if (n > SCAP) n = SCAP;
    int qi = qbase + w;
    for (unsigned int j = lane; j < n; j += 64) {
      unsigned long long my = surv[w][j];
      int rank = 0;
      unsigned int t = 0;
      for (; t + 4 <= n; t += 4) {  // 4 independent LDS loads per iter
        unsigned long long s0 = surv[w][t + 0];
        unsigned long long s1 = surv[w][t + 1];
        unsigned long long s2 = surv[w][t + 2];
        unsigned long long s3 = surv[w][t + 3];
        rank += ((s0 < my) ? 1 : 0) + ((s1 < my) ? 1 : 0) +
                ((s2 < my) ? 1 : 0) + ((s3 < my) ? 1 : 0);
      }
      for (; t < n; t++) rank += (surv[w][t] < my) ? 1 : 0;
      if (rank < KZ) {
        int idx = (int)(my & 0x1FFFull);
        nidx[w][rank] = idx;
        float fi = (float)idx;
        out[O_EDGE + qi * KZ + rank] = fi;                   // edge_index
        out[O_FE + qi * KZ + rank] = fi;                     // full_edge row0
        out[O_FE + NNODES * KZ + qi * KZ + rank] = (float)qi;  // full_edge row1
      }
    }
  }
  __syncthreads();
  // ---- x-copy store (prefetched at entry; fire-and-forget) ----
  ((float4*)out)[(size_t)(qbase + xq) * 80 + xc] = xval;
  // ---- gather tail: wave w serves query w, lanes 0..19 ----
  int qi = qbase + w;
  if (lane < KZ) {
    const float4* af = (const float4*)affines + (size_t)qi * 3;
    float4 a0 = af[0], a1 = af[1], a2 = af[2];
    float tx = a0.w, ty = a1.w, tz = a2.w;
    int idx = nidx[w][lane];
    float4 p = pos4[idx];
    float bx = p.x - tx, by = p.y - ty, bz = p.z - tz;
    // einsum('nji,nkj->nki'): v_i = sum_j rot[j][i]*b_j (rot^T; NOT orthogonal)
    float vx = a0.x * bx + a1.x * by + a2.x * bz;
    float vy = a0.y * bx + a1.y * by + a2.y * bz;
    float vz = a0.z * bx + a1.z * by + a2.z * bz;
    out[O_NBP + qi * 60 + lane * 3 + 0] = vx;
    out[O_NBP + qi * 60 + lane * 3 + 1] = vy;
    out[O_NBP + qi * 60 + lane * 3 + 2] = vz;
    float dn = sqrtf(vx * vx + vy * vy + vz * vz);
    dnbuf[w][lane] = dn;  // NBD sincos in all-thread phase below
    float4 cn = ncac4[(size_t)qi * 3 + 0];   // n_pos
    float4 ca = ncac4[(size_t)qi * 3 + 1];   // ca_pos
    float4 cc = ncac4[(size_t)qi * 3 + 2];   // c_pos
    float4 nb0 = ncac4[(size_t)idx * 3 + 0];
    float4 nb1 = ncac4[(size_t)idx * 3 + 1];
    float4 nb2 = ncac4[(size_t)idx * 3 + 2];
    auto dist = [](float4 a, float4 b) {
      float dx = a.x - b.x, dy = a.y - b.y, dz = a.z - b.z;
      return sqrtf(dx * dx + dy * dy + dz * dz);
    };
    distbuf[w][lane * 3 + 0] = dist(nb0, ca);
    distbuf[w][lane * 3 + 1] = dist(nb1, ca);
    distbuf[w][lane * 3 + 2] = dist(nb2, ca);
    distbuf[w][60 + lane] = dist(nb2, cn);  // n_to_c
    distbuf[w][80 + lane] = dist(nb0, cc);  // c_to_n
  }
  __syncthreads();
  // ---- NBD sinusoidal encode: 1600 (q,nb,j) items over 512 threads ----
  for (int u = tid; u < QB * KZ * 10; u += NTH) {
    int q = u / 200, rem = u - q * 200;
    int nb = rem / 10, j = rem - nb * 10;
    float a = dnbuf[q][nb] * FREQS[j];
    int base = O_NBD + (qbase + q) * 400 + nb * 20 + j;
    out[base] = __sinf(a);
    out[base + 10] = __cosf(a);
  }
  // ---- raw distance staging for k_gemm: 8 rows x 100 f32, coalesced ----
  for (int u = tid; u < QB * 100; u += NTH) {
    int q = u / 100, col = u - q * 100;
    dstg[(size_t)(qbase + q) * 100 + col] = distbuf[q][col];
  }
}

// ---------------- MFMA GEMM with in-kernel sinusoid encode (UNCHANGED R3) ----------------
// Stage: 16 rows x 100 raw distances -> enc bf16 A-tile in LDS (identical
// f2bf(__sinf(d*FREQS[j])) bits as before -> identical MFMA inputs).
// MFMA chains and reduce order UNCHANGED -> bit-identical output.
__global__ __launch_bounds__(512) void k_gemm(const float* __restrict__ dstg,
                                              const unsigned short* __restrict__ wtb,
                                              float* __restrict__ out) {
  __shared__ unsigned short albs[16][2056];  // 65.8 KB A-tile
  __shared__ float red[4][16][68];           // +4 pad: conflict-free
  int tid = threadIdx.x;
  int m0 = blockIdx.x * 16;
  // ---- stage: 1600 (row,col) pairs over 512 threads ----
  for (int u = tid; u < 1600; u += 512) {
    int row = u / 100, col = u - row * 100;
    float d = dstg[(size_t)(m0 + row) * 100 + col];
    unsigned short sh[20];
#pragma unroll
    for (int j = 0; j < 10; j++) {
      float a = d * FREQS[j];
      sh[j] = f2bf(__sinf(a));
      sh[10 + j] = f2bf(__cosf(a));
    }
    unsigned int* dst = (unsigned int*)&albs[row][col * 20];
#pragma unroll
    for (int wq = 0; wq < 10; wq++)
      dst[wq] = (unsigned int)sh[2 * wq] | ((unsigned int)sh[2 * wq + 1] << 16);
  }
  // ---- zero K-pad cols [2000,2056): 28 u32 per row x 16 rows ----
  for (int u = tid; u < 16 * 28; u += 512) {
    int row = u / 28, wd = u - row * 28;
    ((unsigned int*)&albs[row][2000])[wd] = 0u;
  }
  __syncthreads();
  int w = tid >> 6, lane = tid & 63;  // w in 0..7
  int kq = w & 3, nh = w >> 2;        // k-quarter, n-half
  int am = lane & 15, ak = (lane >> 4) * 8;
  const unsigned short* arow = &albs[am][kq * 512 + ak];
  const unsigned short* brow = wtb + (size_t)(am + nh * 32) * 2048 + kq * 512 + ak;
  f32x4 acc0 = {0.f, 0.f, 0.f, 0.f}, acc1 = acc0;
#pragma unroll 8
  for (int ks = 0; ks < 16; ks++) {
    bfrag a = *(const bfrag*)(arow + ks * 32);
    bfrag b0 = *(const bfrag*)(brow + ks * 32);
    bfrag b1 = *(const bfrag*)(brow + 16 * 2048 + ks * 32);
    acc0 = __builtin_amdgcn_mfma_f32_16x16x32_bf16(a, b0, acc0, 0, 0, 0);
    acc1 = __builtin_amdgcn_mfma_f32_16x16x32_bf16(a, b1, acc1, 0, 0, 0);
  }
  {  // write partials: row=(lane>>4)*4+r, col=lane&15 (+16 per tile, +32 per nh)
    int rm = (lane >> 4) * 4, cn = lane & 15;
#pragma unroll
    for (int r = 0; r < 4; r++) {
      red[kq][rm + r][nh * 32 + cn]      = acc0[r];
      red[kq][rm + r][nh * 32 + 16 + cn] = acc1[r];
    }
  }
  __syncthreads();
  if (tid < 256) {
    // reduce 4 partials; 256 threads x one float4 = 16 rows x 64 cols
    int m = tid >> 4, n = (tid & 15) * 4;
    float4 s0 = *(const float4*)&red[0][m][n];
    float4 s1 = *(const float4*)&red[1][m][n];
    float4 s2 = *(const float4*)&red[2][m][n];
    float4 s3 = *(const float4*)&red[3][m][n];
    float4 s = make_float4(s0.x + s1.x + s2.x + s3.x, s0.y + s1.y + s2.y + s3.y,
                           s0.z + s1.z + s2.z + s3.z, s0.w + s1.w + s2.w + s3.w);
    *(float4*)&out[(size_t)(m0 + m) * 320 + 256 + n] = s;
  }
}

extern "C" void kernel_launch(void* const* d_in, const int* in_sizes, int n_in,
                              void* d_out, int out_size, void* d_ws, size_t ws_size,
                              hipStream_t stream) {
  const float* x = (const float*)d_in[0];
  const float* affines = (const float*)d_in[1];
  const float* ne_w = (const float*)d_in[2];
  const float* lit = (const float*)d_in[3];
  const int* mask = (const int*)d_in[4];
  float* out = (float*)d_out;
  char* ws = (char*)d_ws;
  // ws layout (bytes)
  float4* pos4 = (float4*)(ws + 0);                   //  8192*16   = 131072
  float4* ncac4 = (float4*)(ws + 131072);             //  8192*48   -> 524288
  unsigned short* wtb = (unsigned short*)(ws + 524288);   // 64*2048*2 -> 786432
  float* dstg = (float*)(ws + 786432);                // 8192*100*4 -> 4063232

  k_pre<<<512, 256, 0, stream>>>(affines, mask, lit, ne_w, out, pos4, ncac4, wtb);
  k_knng<<<NNODES / QB, NTH, 0, stream>>>(pos4, affines, ncac4, (const float4*)x, out, dstg);
  k_gemm<<<512, 512, 0, stream>>>(dstg, wtb, out);
}

// Round 5
// 115.205 us; speedup vs baseline: 1.0860x; 1.0860x over previous
//
#include <hip/hip_runtime.h>

#define NNODES 8192
#define KZ 20
#define QB 16     // queries per block (R5: one block == one 16-row gemm tile)
#define NTH 512
#define SCAP 192  // survivor cap per query; E[n]~45, bounds-guarded

// freqs[j] = 50^(-j/10)
static constexpr float FREQS[10] = {
  1.0f, 0.67624323f, 0.45730491f, 0.30924935f, 0.20912778f,
  0.14142136f, 0.09563524f, 0.06467268f, 0.04373443f, 0.02957512f};

// output offsets (floats)
#define O_XNE  0
#define O_POS  2621440
#define O_NBP  2646016
#define O_NBD  3137536
#define O_EDGE 6414336
#define O_FE   6578176

typedef __attribute__((ext_vector_type(8))) short bfrag;   // 8 bf16 (4 VGPRs)
typedef __attribute__((ext_vector_type(4))) float f32x4;   // MFMA C/D

static __device__ __forceinline__ unsigned short f2bf(float f) {
  unsigned int u = __float_as_uint(f);
  u += 0x7fffu + ((u >> 16) & 1u);
  return (unsigned short)(u >> 16);
}
// wave64 max-reduce via DPP (verified pattern), broadcast to all lanes.
static __device__ __forceinline__ float wave_max_f32(float v) {
  float t;
  t = __builtin_bit_cast(float, __builtin_amdgcn_update_dpp(__builtin_bit_cast(int, v), __builtin_bit_cast(int, v), 0x111, 0xF, 0xF, false)); v = fmaxf(v, t); // row_shr:1
  t = __builtin_bit_cast(float, __builtin_amdgcn_update_dpp(__builtin_bit_cast(int, v), __builtin_bit_cast(int, v), 0x112, 0xF, 0xF, false)); v = fmaxf(v, t); // row_shr:2
  t = __builtin_bit_cast(float, __builtin_amdgcn_update_dpp(__builtin_bit_cast(int, v), __builtin_bit_cast(int, v), 0x114, 0xF, 0xF, false)); v = fmaxf(v, t); // row_shr:4
  t = __builtin_bit_cast(float, __builtin_amdgcn_update_dpp(__builtin_bit_cast(int, v), __builtin_bit_cast(int, v), 0x118, 0xF, 0xF, false)); v = fmaxf(v, t); // row_shr:8
  t = __builtin_bit_cast(float, __builtin_amdgcn_update_dpp(__builtin_bit_cast(int, v), __builtin_bit_cast(int, v), 0x142, 0xF, 0xF, false)); v = fmaxf(v, t); // row_bcast:15
  t = __builtin_bit_cast(float, __builtin_amdgcn_update_dpp(__builtin_bit_cast(int, v), __builtin_bit_cast(int, v), 0x143, 0xF, 0xF, false)); v = fmaxf(v, t); // row_bcast:31
  return __builtin_bit_cast(float, __builtin_amdgcn_readlane(__builtin_bit_cast(int, v), 63));
}

// ---------------- prep + Wt bf16 cast (UNCHANGED) ----------------
__global__ __launch_bounds__(256) void k_pre(const float* __restrict__ affines,
                                             const int* __restrict__ prot_mask,
                                             const float* __restrict__ lit,
                                             const float* __restrict__ w,
                                             float* __restrict__ out,
                                             float4* __restrict__ pos4,
                                             float4* __restrict__ ncac4,
                                             unsigned short* __restrict__ wtb) {
  int t = blockIdx.x * 256 + threadIdx.x;  // < 131072
  {  // bf16 cast of ne_weight -> wtb[64][2048] (K-contiguous, zero pad)
    int o = t >> 11, k = t & 2047;
    wtb[t] = (k < 2000) ? f2bf(w[(size_t)o * 2000 + k]) : (unsigned short)0;
  }
  if (t < NNODES) {  // prep: positions, n2, ncac
    int n = t;
    const float4* af = (const float4*)affines + (size_t)n * 3;
    float4 a0 = af[0], a1 = af[1], a2 = af[2];  // rows of rot, .w = trans
    float tx = a0.w, ty = a1.w, tz = a2.w;
    float n2;
    {
#pragma clang fp contract(off)
      float xx = tx * tx;
      float yy = ty * ty;
      float zz = tz * tz;
      n2 = (xx + yy) + zz;
    }
    pos4[n] = make_float4(tx, ty, tz, n2);
    out[O_POS + n * 3 + 0] = tx;
    out[O_POS + n * 3 + 1] = ty;
    out[O_POS + n * 3 + 2] = tz;
    int aat = (prot_mask[n] != 0) ? 0 : 20;
    const float* lp = lit + aat * 9;
#pragma unroll
    for (int a = 0; a < 3; a++) {
      float l0 = lp[a * 3 + 0], l1 = lp[a * 3 + 1], l2 = lp[a * 3 + 2];
      float x = a0.x * l0 + a0.y * l1 + a0.z * l2 + tx;
      float y = a1.x * l0 + a1.y * l1 + a1.z * l2 + ty;
      float z = a2.x * l0 + a2.y * l1 + a2.z * l2 + tz;
      ncac4[n * 3 + a] = make_float4(x, y, z, 0.f);
    }
  }
}

// ---------------- FUSED KNN + gather + MFMA GEMM: QB=16, 512 threads ----------------
// d2 arithmetic bit-identical to all passing rounds:
//   dot = fmaf(z,pcz, fmaf(y,pcy, x*pcx)); d2 = fmaf(-2, dot, n2q + n2c)
// Pivot partitions: 64 groups of (8 threads x 16 cands) = 128 cands -- SAME
// granularity as all passing rounds; pivot = 21st-smallest group min => all
// true top-20 <= pivot; exact u64 (key<<13|idx) rank-select -> identical
// top-20. Waves handle 2 query-rounds (q = w, w+8). GEMM tail: A-tile staged
// from distbuf (same f32 bits -> same f2bf(sinf) bits), same kq-quartered
// MFMA chains, same s0+s1+s2+s3 reduce order -> BIT-IDENTICAL output.
// red[] overlays the albs region behind a barrier (albs dead after MFMA).
__global__ __launch_bounds__(512, 4) void k_knng(const float4* __restrict__ pos4,
                                                 const float* __restrict__ affines,
                                                 const float4* __restrict__ ncac4,
                                                 const float4* __restrict__ x4,
                                                 const unsigned short* __restrict__ wtb,
                                                 float* __restrict__ out) {
  __shared__ __align__(16) union {
    struct {
      float mca[QB][64];                   //  4 KB group minima
      unsigned long long surv[QB][SCAP];   // 24 KB
      unsigned short jobs[QB * NTH];       // 16 KB (max-sized: no guard needed)
      float dnbuf[QB][KZ];
      int nidx[QB][KZ];
      float pivots[QB];
      unsigned int cnt[QB];
      unsigned int njobs;
    } k;                                    // ~47.8 KB
    unsigned short albs[16][2056];          // 65.8 KB gemm A-tile
    float red[4][16][68];                   // 17.4 KB overlay (after albs dead)
  } u;
  __shared__ float distbuf[QB][100];        // 6.4 KB, persists knng->gemm
  int tid = threadIdx.x;
  int lane = tid & 63, w = tid >> 6;        // w in 0..7
  int qbase = blockIdx.x * QB;
  // x-copy prefetch: 16 rows x 64 float4 = 1024 items, 2 per thread.
  int xr0 = tid >> 6, xc0 = tid & 63;            // item tid
  int xr1 = (tid + 512) >> 6, xc1 = tid & 63;    // item tid+512
  float4 xv0 = x4[(size_t)(qbase + xr0) * 64 + xc0];
  float4 xv1 = x4[(size_t)(qbase + xr1) * 64 + xc1];
  // 16 query positions: wave-uniform
  float4 q0 = pos4[qbase + 0],  q1 = pos4[qbase + 1],  q2 = pos4[qbase + 2],  q3 = pos4[qbase + 3];
  float4 q4 = pos4[qbase + 4],  q5 = pos4[qbase + 5],  q6 = pos4[qbase + 6],  q7 = pos4[qbase + 7];
  float4 q8 = pos4[qbase + 8],  q9 = pos4[qbase + 9],  q10 = pos4[qbase + 10], q11 = pos4[qbase + 11];
  float4 q12 = pos4[qbase + 12], q13 = pos4[qbase + 13], q14 = pos4[qbase + 14], q15 = pos4[qbase + 15];
  const float4* pp = pos4 + tid;
  float l0, l1, l2, l3, l4, l5, l6, l7, l8, l9, l10, l11, l12, l13, l14, l15;
  l0 = l1 = l2 = l3 = l4 = l5 = l6 = l7 = l8 = l9 = l10 = l11 = l12 = l13 = l14 = l15 = __builtin_inff();
  {  // ---- pass 1: per-thread minima, 16 cands (stride 512) x 16 queries ----
#pragma clang fp contract(off)
#define DQ(i) { float d = fmaf(-2.0f, fmaf(q##i.z, pc.z, fmaf(q##i.y, pc.y, q##i.x * pc.x)), q##i.w + pc.w); l##i = fminf(l##i, d); }
#pragma unroll 2
    for (int s = 0; s < 16; s++) {
      float4 pc = pp[s << 9];
      DQ(0) DQ(1) DQ(2) DQ(3) DQ(4) DQ(5) DQ(6) DQ(7)
      DQ(8) DQ(9) DQ(10) DQ(11) DQ(12) DQ(13) DQ(14) DQ(15)
    }
#undef DQ
  }
  {  // ---- group-of-8 minima via shfl_xor -> mca ----
#define GM(i) { float v = l##i; v = fminf(v, __shfl_xor(v, 1)); v = fminf(v, __shfl_xor(v, 2)); v = fminf(v, __shfl_xor(v, 4)); if ((tid & 7) == 0) u.k.mca[i][tid >> 3] = v; }
    GM(0) GM(1) GM(2) GM(3) GM(4) GM(5) GM(6) GM(7)
    GM(8) GM(9) GM(10) GM(11) GM(12) GM(13) GM(14) GM(15)
#undef GM
  }
  if (tid == 0) u.k.njobs = 0u;
  __syncthreads();
  {  // ---- pivots: wave w handles queries w and w+8 ----
#pragma unroll
    for (int r = 0; r < 2; r++) {
      int q = w + 8 * r;
      float m = u.k.mca[q][lane];
      int c = 0;
#pragma unroll 8
      for (int j = 0; j < 64; j++) c += (u.k.mca[q][j] < m) ? 1 : 0;
      float elig = (c < KZ + 1) ? m : -__builtin_inff();
      float piv = wave_max_f32(elig);
      if (lane == 0) { u.k.pivots[q] = piv; u.k.cnt[q] = 0u; }
    }
  }
  __syncthreads();
  {  // ---- job build: (q,owner) qualifies iff pass-1 min <= pivot_q ----
#define JB(i) if (l##i <= u.k.pivots[i]) { unsigned int ix = atomicAdd(&u.k.njobs, 1u); u.k.jobs[ix] = (unsigned short)((i << 9) | tid); }
    JB(0) JB(1) JB(2) JB(3) JB(4) JB(5) JB(6) JB(7)
    JB(8) JB(9) JB(10) JB(11) JB(12) JB(13) JB(14) JB(15)
#undef JB
  }
  __syncthreads();
  {  // ---- pass 2 (compacted): each job rescans its owner's 16 cands, 1 query ----
#pragma clang fp contract(off)
    unsigned int nj = u.k.njobs;
    for (unsigned int j = tid; j < nj; j += NTH) {
      int job = u.k.jobs[j];
      int q = job >> 9, owner = job & 511;
      int qidx = qbase + q;
      float4 qv = pos4[qidx];
      float pv = u.k.pivots[q];
      const float4* src = pos4 + owner;
#pragma unroll 8
      for (int s = 0; s < 16; s++) {
        float4 pc = src[s << 9];
        float dot = fmaf(qv.z, pc.z, fmaf(qv.y, pc.y, qv.x * pc.x));
        float d2 = fmaf(-2.0f, dot, qv.w + pc.w);
        int cc = (s << 9) + owner;
        if (d2 <= pv && cc != qidx) {
          unsigned int b = __float_as_uint(d2);
          unsigned int k = (b & 0x80000000u) ? ~b : (b | 0x80000000u);
          unsigned int ix = atomicAdd(&u.k.cnt[q], 1u);
          if (ix < SCAP)  // guard (never hit for this data)
            u.k.surv[q][ix] = ((unsigned long long)k << 13) | (unsigned int)cc;
        }
      }
    }
  }
  __syncthreads();
  {  // ---- exact rank-select: wave w handles queries w, w+8 ----
#pragma unroll
    for (int r = 0; r < 2; r++) {
      int q = w + 8 * r;
      unsigned int n = u.k.cnt[q]; if (n > SCAP) n = SCAP;
      int qi = qbase + q;
      for (unsigned int j = lane; j < n; j += 64) {
        unsigned long long my = u.k.surv[q][j];
        int rank = 0;
        unsigned int t = 0;
        for (; t + 4 <= n; t += 4) {
          unsigned long long s0 = u.k.surv[q][t + 0];
          unsigned long long s1 = u.k.surv[q][t + 1];
          unsigned long long s2 = u.k.surv[q][t + 2];
          unsigned long long s3 = u.k.surv[q][t + 3];
          rank += ((s0 < my) ? 1 : 0) + ((s1 < my) ? 1 : 0) +
                  ((s2 < my) ? 1 : 0) + ((s3 < my) ? 1 : 0);
        }
        for (; t < n; t++) rank += (u.k.surv[q][t] < my) ? 1 : 0;
        if (rank < KZ) {
          int idx = (int)(my & 0x1FFFull);
          u.k.nidx[q][rank] = idx;
          float fi = (float)idx;
          out[O_EDGE + qi * KZ + rank] = fi;                     // edge_index
          out[O_FE + qi * KZ + rank] = fi;                       // full_edge row0
          out[O_FE + NNODES * KZ + qi * KZ + rank] = (float)qi;  // full_edge row1
        }
      }
    }
  }
  __syncthreads();
  // ---- x-copy store (prefetched at entry; fire-and-forget) ----
  ((float4*)out)[(size_t)(qbase + xr0) * 80 + xc0] = xv0;
  ((float4*)out)[(size_t)(qbase + xr1) * 80 + xc1] = xv1;
  {  // ---- gather tail: wave w serves queries w, w+8 on lanes 0..19 ----
#pragma unroll
    for (int r = 0; r < 2; r++) {
      int q = w + 8 * r;
      int qi = qbase + q;
      if (lane < KZ) {
        const float4* af = (const float4*)affines + (size_t)qi * 3;
        float4 a0 = af[0], a1 = af[1], a2 = af[2];
        float tx = a0.w, ty = a1.w, tz = a2.w;
        int idx = u.k.nidx[q][lane];
        float4 p = pos4[idx];
        float bx = p.x - tx, by = p.y - ty, bz = p.z - tz;
        // einsum('nji,nkj->nki'): v_i = sum_j rot[j][i]*b_j (rot^T)
        float vx = a0.x * bx + a1.x * by + a2.x * bz;
        float vy = a0.y * bx + a1.y * by + a2.y * bz;
        float vz = a0.z * bx + a1.z * by + a2.z * bz;
        out[O_NBP + qi * 60 + lane * 3 + 0] = vx;
        out[O_NBP + qi * 60 + lane * 3 + 1] = vy;
        out[O_NBP + qi * 60 + lane * 3 + 2] = vz;
        float dn = sqrtf(vx * vx + vy * vy + vz * vz);
        u.k.dnbuf[q][lane] = dn;
        float4 cn = ncac4[(size_t)qi * 3 + 0];   // n_pos
        float4 ca = ncac4[(size_t)qi * 3 + 1];   // ca_pos
        float4 cc = ncac4[(size_t)qi * 3 + 2];   // c_pos
        float4 nb0 = ncac4[(size_t)idx * 3 + 0];
        float4 nb1 = ncac4[(size_t)idx * 3 + 1];
        float4 nb2 = ncac4[(size_t)idx * 3 + 2];
        auto dist = [](float4 a, float4 b) {
          float dx = a.x - b.x, dy = a.y - b.y, dz = a.z - b.z;
          return sqrtf(dx * dx + dy * dy + dz * dz);
        };
        distbuf[q][lane * 3 + 0] = dist(nb0, ca);
        distbuf[q][lane * 3 + 1] = dist(nb1, ca);
        distbuf[q][lane * 3 + 2] = dist(nb2, ca);
        distbuf[q][60 + lane] = dist(nb2, cn);  // n_to_c
        distbuf[q][80 + lane] = dist(nb0, cc);  // c_to_n
      }
    }
  }
  __syncthreads();
  // ---- NBD sinusoidal encode: 3200 (q,nb,j) items over 512 threads ----
  for (int uu = tid; uu < QB * KZ * 10; uu += NTH) {
    int q = uu / 200, rem = uu - q * 200;
    int nb = rem / 10, j = rem - nb * 10;
    float a = u.k.dnbuf[q][nb] * FREQS[j];
    int base = O_NBD + (qbase + q) * 400 + nb * 20 + j;
    out[base] = __sinf(a);
    out[base + 10] = __cosf(a);
  }
  __syncthreads();  // k-region (dnbuf) dead; albs staging may now clobber union
  // ================= GEMM tail (bit-identical to prior k_gemm) =================
  {  // ---- stage A-tile: 1600 (row,col) pairs; same f2bf(sinf) bits ----
    for (int uu = tid; uu < 1600; uu += NTH) {
      int row = uu / 100, col = uu - row * 100;
      float d = distbuf[row][col];
      unsigned short sh[20];
#pragma unroll
      for (int j = 0; j < 10; j++) {
        float a = d * FREQS[j];
        sh[j] = f2bf(__sinf(a));
        sh[10 + j] = f2bf(__cosf(a));
      }
      unsigned int* dst = (unsigned int*)&u.albs[row][col * 20];
#pragma unroll
      for (int wq = 0; wq < 10; wq++)
        dst[wq] = (unsigned int)sh[2 * wq] | ((unsigned int)sh[2 * wq + 1] << 16);
    }
    // zero K-pad cols [2000,2048): 24 u32 per row x 16 rows
    for (int uu = tid; uu < 16 * 24; uu += NTH) {
      int row = uu / 24, wd = uu - row * 24;
      ((unsigned int*)&u.albs[row][2000])[wd] = 0u;
    }
  }
  __syncthreads();
  int m0 = qbase;
  int kq = w & 3, nh = w >> 2;        // k-quarter, n-half
  int am = lane & 15, ak = (lane >> 4) * 8;
  const unsigned short* arow = &u.albs[am][kq * 512 + ak];
  const unsigned short* brow = wtb + (size_t)(am + nh * 32) * 2048 + kq * 512 + ak;
  f32x4 acc0 = {0.f, 0.f, 0.f, 0.f}, acc1 = acc0;
#pragma unroll 8
  for (int ks = 0; ks < 16; ks++) {
    bfrag a = *(const bfrag*)(arow + ks * 32);
    bfrag b0 = *(const bfrag*)(brow + ks * 32);
    bfrag b1 = *(const bfrag*)(brow + 16 * 2048 + ks * 32);
    acc0 = __builtin_amdgcn_mfma_f32_16x16x32_bf16(a, b0, acc0, 0, 0, 0);
    acc1 = __builtin_amdgcn_mfma_f32_16x16x32_bf16(a, b1, acc1, 0, 0, 0);
  }
  __syncthreads();  // all albs reads done; red may overlay
  {  // write partials: row=(lane>>4)*4+r_, col=lane&15 (+16 per tile, +32 per nh)
    int rm = (lane >> 4) * 4, cn = lane & 15;
#pragma unroll
    for (int r_ = 0; r_ < 4; r_++) {
      u.red[kq][rm + r_][nh * 32 + cn]      = acc0[r_];
      u.red[kq][rm + r_][nh * 32 + 16 + cn] = acc1[r_];
    }
  }
  __syncthreads();
  if (tid < 256) {
    // reduce 4 partials; 256 threads x one float4 = 16 rows x 64 cols
    int m = tid >> 4, n = (tid & 15) * 4;
    float4 s0 = *(const float4*)&u.red[0][m][n];
    float4 s1 = *(const float4*)&u.red[1][m][n];
    float4 s2 = *(const float4*)&u.red[2][m][n];
    float4 s3 = *(const float4*)&u.red[3][m][n];
    float4 s = make_float4(s0.x + s1.x + s2.x + s3.x, s0.y + s1.y + s2.y + s3.y,
                           s0.z + s1.z + s2.z + s3.z, s0.w + s1.w + s2.w + s3.w);
    *(float4*)&out[(size_t)(m0 + m) * 320 + 256 + n] = s;
  }
}

extern "C" void kernel_launch(void* const* d_in, const int* in_sizes, int n_in,
                              void* d_out, int out_size, void* d_ws, size_t ws_size,
                              hipStream_t stream) {
  const float* x = (const float*)d_in[0];
  const float* affines = (const float*)d_in[1];
  const float* ne_w = (const float*)d_in[2];
  const float* lit = (const float*)d_in[3];
  const int* mask = (const int*)d_in[4];
  float* out = (float*)d_out;
  char* ws = (char*)d_ws;
  // ws layout (bytes)
  float4* pos4 = (float4*)(ws + 0);                   //  8192*16   = 131072
  float4* ncac4 = (float4*)(ws + 131072);             //  8192*48   -> 524288
  unsigned short* wtb = (unsigned short*)(ws + 524288);   // 64*2048*2 -> 786432

  k_pre<<<512, 256, 0, stream>>>(affines, mask, lit, ne_w, out, pos4, ncac4, wtb);
  k_knng<<<NNODES / QB, NTH, 0, stream>>>(pos4, affines, ncac4, (const float4*)x, wtb, out);
}